// Round 14
// baseline (831.658 us; speedup 1.0000x reference)
//
#include <hip/hip_runtime.h>
#include <math.h>

#define NNODES 50000
#define NEDGES 800000
#define NB 196  // ceil(NNODES/256)

// ---------- reduction helpers (wave = 64 lanes) ----------
__device__ __forceinline__ float wave_sum(float v) {
#pragma unroll
  for (int o = 32; o > 0; o >>= 1) v += __shfl_xor(v, o, 64);
  return v;
}
__device__ __forceinline__ float wave_max(float v) {
#pragma unroll
  for (int o = 32; o > 0; o >>= 1) v = fmaxf(v, __shfl_xor(v, o, 64));
  return v;
}
__device__ __forceinline__ int wave_isum(int v) {
#pragma unroll
  for (int o = 32; o > 0; o >>= 1) v += __shfl_xor(v, o, 64);
  return v;
}
__device__ __forceinline__ int wave_iscan(int v, int lane) {  // inclusive
#pragma unroll
  for (int o = 1; o < 64; o <<= 1) {
    int u = __shfl_up(v, o, 64);
    if (lane >= o) v += u;
  }
  return v;
}
template <int NW>
__device__ __forceinline__ float block_sum(float v, float* red) {
  v = wave_sum(v);
  __syncthreads();
  if ((threadIdx.x & 63) == 0) red[threadIdx.x >> 6] = v;
  __syncthreads();
  float s = 0.f;
#pragma unroll
  for (int i = 0; i < NW; i++) s += red[i];
  return s;
}

__device__ __forceinline__ float leaky02(float x) { return x > 0.f ? x : 0.2f * x; }

__device__ __forceinline__ void atomicMaxFloat(float* addr, float val) {
  if (val >= 0.f)
    atomicMax((int*)addr, __float_as_int(val));
  else
    atomicMin((unsigned int*)addr, __float_as_uint(val));
}

// ---------- init ----------
__global__ void k_init(int* __restrict__ deg, float* __restrict__ scal,
                       float* __restrict__ pooled) {
  int i = blockIdx.x * blockDim.x + threadIdx.x;
  if (i < NNODES) deg[i] = 0;
  if (i < 256) pooled[i] = 0.f;
  if (i == 0) { scal[0] = -3.0e38f; scal[1] = 0.f; }
}

// ---------- degree count (in-degree by dst) ----------
__global__ void k_deg(const int* __restrict__ dst, int* __restrict__ deg) {
  int e = blockIdx.x * blockDim.x + threadIdx.x;
  if (e < NEDGES) atomicAdd(&deg[dst[e]], 1);
}

// ---------- hierarchical scan stage 1: per-block degree sums ----------
__global__ __launch_bounds__(256) void k_scan1(const int* __restrict__ deg,
                                               int* __restrict__ bsum) {
  __shared__ int red[4];
  int i = blockIdx.x * 256 + threadIdx.x;
  int v = (i < NNODES) ? deg[i] : 0;
  v = wave_isum(v);
  if ((threadIdx.x & 63) == 0) red[threadIdx.x >> 6] = v;
  __syncthreads();
  if (threadIdx.x == 0) bsum[blockIdx.x] = red[0] + red[1] + red[2] + red[3];
}

// ---------- stage 2: exclusive scan of block sums (1 block) ----------
__global__ __launch_bounds__(256) void k_scan2(const int* __restrict__ bsum,
                                               int* __restrict__ bbase) {
  __shared__ int wsum[4];
  const int t = threadIdx.x, lane = t & 63, w = t >> 6;
  int v = (t < NB) ? bsum[t] : 0;
  int incl = wave_iscan(v, lane);
  if (lane == 63) wsum[w] = incl;
  __syncthreads();
  int wb = 0;
  for (int k = 0; k < w; k++) wb += wsum[k];
  if (t < NB) bbase[t] = wb + incl - v;  // exclusive prefix
}

// ---------- stage 3: per-node offsets + cursor + dinv (coalesced) ----------
__global__ __launch_bounds__(256) void k_scan3(const int* __restrict__ deg,
                                               const int* __restrict__ bbase,
                                               int* __restrict__ offs,
                                               int* __restrict__ cursor,
                                               float* __restrict__ dinv) {
  __shared__ int wsum[4];
  const int i = blockIdx.x * 256 + threadIdx.x;
  const int lane = threadIdx.x & 63, w = threadIdx.x >> 6;
  int d = (i < NNODES) ? deg[i] : 0;
  int incl = wave_iscan(d, lane);
  if (lane == 63) wsum[w] = incl;
  __syncthreads();
  int wb = 0;
  for (int k = 0; k < w; k++) wb += wsum[k];
  int excl = bbase[blockIdx.x] + wb + incl - d;
  if (i < NNODES) {
    offs[i] = excl;
    cursor[i] = excl;
    dinv[i] = rsqrtf((float)(d + 1));  // +1 self-loop
    if (i == NNODES - 1) offs[NNODES] = excl + d;
  }
}

// ---------- CSR fill ----------
__global__ void k_fill(const int* __restrict__ src, const int* __restrict__ dst,
                       int* __restrict__ cursor, int* __restrict__ csr) {
  int e = blockIdx.x * blockDim.x + threadIdx.x;
  if (e >= NEDGES) return;
  int d = dst[e];
  int p = atomicAdd(&cursor[d], 1);
  csr[p] = src[e];
}

// ---------- agg0 = Ahat @ x  (3-dim rows, thread per node) ----------
__global__ void k_agg3(const float* __restrict__ x, const float* __restrict__ dinv,
                       const int* __restrict__ offs, const int* __restrict__ csr,
                       float* __restrict__ agg0) {
  int n = blockIdx.x * blockDim.x + threadIdx.x;
  if (n >= NNODES) return;
  float di = dinv[n];
  float a0 = di * x[n * 3], a1 = di * x[n * 3 + 1], a2 = di * x[n * 3 + 2];
  int lo = offs[n], hi = offs[n + 1];
  int p = lo;
  int snext = (p < hi) ? csr[p] : 0;
  while (p < hi) {
    int s = snext; p++; if (p < hi) snext = csr[p];
    float w = dinv[s];
    a0 = fmaf(w, x[s * 3], a0);
    a1 = fmaf(w, x[s * 3 + 1], a1);
    a2 = fmaf(w, x[s * 3 + 2], a2);
  }
  agg0[n * 3] = di * a0; agg0[n * 3 + 1] = di * a1; agg0[n * 3 + 2] = di * a2;
}

// ---------- aggD = Ahat @ h  (D = 64*VEC, block per node, NG edge-groups) ----------
template <int VEC, int NG>
__global__ __launch_bounds__(64 * NG) void k_agg(const float* __restrict__ h,
                                                 const float* __restrict__ dinv,
                                                 const int* __restrict__ offs,
                                                 const int* __restrict__ csr,
                                                 float* __restrict__ out) {
  __shared__ float lacc[NG][64][VEC + 1];
  const int n = blockIdx.x;
  const int lane = threadIdx.x & 63, g = threadIdx.x >> 6;
  const float di = dinv[n];
  float acc[VEC];
#pragma unroll
  for (int v = 0; v < VEC; v++) acc[v] = 0.f;
  if (g == 0) {
    const float* r = h + (size_t)n * (64 * VEC) + lane * VEC;
#pragma unroll
    for (int v = 0; v < VEC; v++) acc[v] = di * r[v];
  }
  const int lo = offs[n], hi = offs[n + 1];
  int p = lo + g;
  int snext = (p < hi) ? csr[p] : 0;
  while (p < hi) {
    int s = snext; p += NG; if (p < hi) snext = csr[p];
    float w = dinv[s];
    const float* r = h + (size_t)s * (64 * VEC) + lane * VEC;
#pragma unroll
    for (int v = 0; v < VEC; v++) acc[v] = fmaf(w, r[v], acc[v]);
  }
#pragma unroll
  for (int v = 0; v < VEC; v++) lacc[g][lane][v] = acc[v];
  __syncthreads();
  if (g == 0) {
#pragma unroll
    for (int G = 1; G < NG; G++)
#pragma unroll
      for (int v = 0; v < VEC; v++) acc[v] += lacc[G][lane][v];
    float* o = out + (size_t)n * (64 * VEC) + lane * VEC;
#pragma unroll
    for (int v = 0; v < VEC; v++) o[v] = di * acc[v];
  }
}

// ---------- Y = LN(act(X@W + b))  node-tiled, fused LN ----------
template <int K, int M, int NT, bool RELU>
__global__ void k_mlp(const float* __restrict__ X, const float* __restrict__ W,
                      const float* __restrict__ b, const float* __restrict__ gam,
                      const float* __restrict__ bet, float* __restrict__ Y) {
  constexpr int NW = M / 64;
  __shared__ float xs[NT * K];
  __shared__ float red[NW];
  const int n0 = blockIdx.x * NT;
  const int j = threadIdx.x;
  const float4* Xt = (const float4*)(X + (size_t)n0 * K);
  for (int i = j; i < NT * K / 4; i += M) ((float4*)xs)[i] = Xt[i];
  __syncthreads();
  float acc[NT];
  float bj = b[j];
#pragma unroll
  for (int r = 0; r < NT; r++) acc[r] = bj;
  for (int k = 0; k < K; k++) {
    float wk = W[k * M + j];
#pragma unroll
    for (int r = 0; r < NT; r++) acc[r] = fmaf(xs[r * K + k], wk, acc[r]);
  }
  float gj = gam[j], btj = bet[j];
  for (int r = 0; r < NT; r++) {
    float a = RELU ? fmaxf(acc[r], 0.f) : acc[r];
    float mu = block_sum<NW>(a, red) * (1.f / M);
    float d = a - mu;
    float var = block_sum<NW>(d * d, red) * (1.f / M);
    Y[(size_t)(n0 + r) * M + j] = fmaf(gj * d, rsqrtf(var + 1e-5f), btj);
  }
}

// ---------- u vectors: u_src[h,k] = sum_c Wg[k, h*64+c] * a_src[h,c] ----------
__global__ void k_uvec(const float* __restrict__ Wg, const float* __restrict__ a_src,
                       const float* __restrict__ a_dst, float* __restrict__ u) {
  const int t = threadIdx.x;  // 512
  const int hh = t >> 7, k = t & 127;
  float us = 0.f, ud = 0.f;
  for (int c = 0; c < 64; c++) {
    float w = Wg[k * 256 + hh * 64 + c];
    us = fmaf(w, a_src[hh * 64 + c], us);
    ud = fmaf(w, a_dst[hh * 64 + c], ud);
  }
  u[t] = us;
  u[512 + t] = ud;
}

// ---------- per-node attention scores: ssrc/sdst[n,h] = x2[n]·u ----------
__global__ __launch_bounds__(256) void k_scores(const float* __restrict__ x2,
                                                const float* __restrict__ u,
                                                float* __restrict__ ssrc,
                                                float* __restrict__ sdst) {
  __shared__ float us[1024];
  const int t = threadIdx.x;
  for (int i = t; i < 1024; i += 256) us[i] = u[i];
  __syncthreads();
  const int n = blockIdx.x * 4 + (t >> 6);
  const int lane = t & 63;
  if (n >= NNODES) return;
  float2 xv = *(const float2*)(x2 + (size_t)n * 128 + lane * 2);
  float d[8];
#pragma unroll
  for (int h = 0; h < 4; h++) {
    d[h] = xv.x * us[h * 128 + lane * 2] + xv.y * us[h * 128 + lane * 2 + 1];
    d[4 + h] = xv.x * us[512 + h * 128 + lane * 2] + xv.y * us[512 + h * 128 + lane * 2 + 1];
  }
#pragma unroll
  for (int o = 32; o > 0; o >>= 1) {
#pragma unroll
    for (int i = 0; i < 8; i++) d[i] += __shfl_xor(d[i], o, 64);
  }
  if (lane == 0) {
    *(float4*)(ssrc + (size_t)n * 4) = make_float4(d[0], d[1], d[2], d[3]);
    *(float4*)(sdst + (size_t)n * 4) = make_float4(d[4], d[5], d[6], d[7]);
  }
}

// ---------- GAT aggregate in x2-space: aggx[n, h, k] = sum_s alpha_s,h x2[s,k] ----------
__global__ __launch_bounds__(256) void k_gatagg(const float* __restrict__ x2,
                                                const float* __restrict__ ssrc,
                                                const float* __restrict__ sdst,
                                                const int* __restrict__ offs,
                                                const int* __restrict__ csr,
                                                float* __restrict__ aggx, int nbase) {
  __shared__ float lm[4][4];
  __shared__ float lden[4][4];
  __shared__ float lacc[4][64][9];
  const int n = nbase + blockIdx.x;
  const int t = threadIdx.x;
  const int lane = t & 63, g = t >> 6;
  const float4 sd = *(const float4*)(sdst + (size_t)n * 4);
  const int lo = offs[n], hi = offs[n + 1];
  float m0 = -3.4e38f, m1 = -3.4e38f, m2 = -3.4e38f, m3 = -3.4e38f;
  float e0x = 0.f, e0y = 0.f, e0z = 0.f, e0w = 0.f;
  if (g == 0) {
    float4 s0 = *(const float4*)(ssrc + (size_t)n * 4);
    e0x = leaky02(s0.x + sd.x); e0y = leaky02(s0.y + sd.y);
    e0z = leaky02(s0.z + sd.z); e0w = leaky02(s0.w + sd.w);
    m0 = e0x; m1 = e0y; m2 = e0z; m3 = e0w;
  }
  for (int p = lo + g; p < hi; p += 4) {
    int s = csr[p];
    float4 ss = *(const float4*)(ssrc + (size_t)s * 4);
    m0 = fmaxf(m0, leaky02(ss.x + sd.x));
    m1 = fmaxf(m1, leaky02(ss.y + sd.y));
    m2 = fmaxf(m2, leaky02(ss.z + sd.z));
    m3 = fmaxf(m3, leaky02(ss.w + sd.w));
  }
  if (lane == 0) { lm[g][0] = m0; lm[g][1] = m1; lm[g][2] = m2; lm[g][3] = m3; }
  __syncthreads();
  const float M0 = fmaxf(fmaxf(lm[0][0], lm[1][0]), fmaxf(lm[2][0], lm[3][0]));
  const float M1 = fmaxf(fmaxf(lm[0][1], lm[1][1]), fmaxf(lm[2][1], lm[3][1]));
  const float M2 = fmaxf(fmaxf(lm[0][2], lm[1][2]), fmaxf(lm[2][2], lm[3][2]));
  const float M3 = fmaxf(fmaxf(lm[0][3], lm[1][3]), fmaxf(lm[2][3], lm[3][3]));
  float den0 = 0.f, den1 = 0.f, den2 = 0.f, den3 = 0.f;
  float a0x = 0.f, a0y = 0.f, a1x = 0.f, a1y = 0.f;
  float a2x = 0.f, a2y = 0.f, a3x = 0.f, a3y = 0.f;
  if (g == 0) {
    float2 xv = *(const float2*)(x2 + (size_t)n * 128 + lane * 2);
    float w;
    w = __expf(e0x - M0); den0 = w; a0x = w * xv.x; a0y = w * xv.y;
    w = __expf(e0y - M1); den1 = w; a1x = w * xv.x; a1y = w * xv.y;
    w = __expf(e0z - M2); den2 = w; a2x = w * xv.x; a2y = w * xv.y;
    w = __expf(e0w - M3); den3 = w; a3x = w * xv.x; a3y = w * xv.y;
  }
  int p = lo + g;
  int snext = (p < hi) ? csr[p] : 0;
  while (p < hi) {
    int s = snext; p += 4; if (p < hi) snext = csr[p];
    float4 ss = *(const float4*)(ssrc + (size_t)s * 4);
    float2 xv = *(const float2*)(x2 + (size_t)s * 128 + lane * 2);
    float w0 = __expf(leaky02(ss.x + sd.x) - M0);
    float w1 = __expf(leaky02(ss.y + sd.y) - M1);
    float w2 = __expf(leaky02(ss.z + sd.z) - M2);
    float w3 = __expf(leaky02(ss.w + sd.w) - M3);
    den0 += w0; den1 += w1; den2 += w2; den3 += w3;
    a0x = fmaf(w0, xv.x, a0x); a0y = fmaf(w0, xv.y, a0y);
    a1x = fmaf(w1, xv.x, a1x); a1y = fmaf(w1, xv.y, a1y);
    a2x = fmaf(w2, xv.x, a2x); a2y = fmaf(w2, xv.y, a2y);
    a3x = fmaf(w3, xv.x, a3x); a3y = fmaf(w3, xv.y, a3y);
  }
  if (lane == 0) { lden[g][0] = den0; lden[g][1] = den1; lden[g][2] = den2; lden[g][3] = den3; }
  lacc[g][lane][0] = a0x; lacc[g][lane][1] = a0y;
  lacc[g][lane][2] = a1x; lacc[g][lane][3] = a1y;
  lacc[g][lane][4] = a2x; lacc[g][lane][5] = a2y;
  lacc[g][lane][6] = a3x; lacc[g][lane][7] = a3y;
  __syncthreads();
  // group g finalizes head g
  float den = lden[0][g] + lden[1][g] + lden[2][g] + lden[3][g] + 1e-16f;
  float ax = lacc[0][lane][2 * g] + lacc[1][lane][2 * g] + lacc[2][lane][2 * g] + lacc[3][lane][2 * g];
  float ay = lacc[0][lane][2 * g + 1] + lacc[1][lane][2 * g + 1] + lacc[2][lane][2 * g + 1] + lacc[3][lane][2 * g + 1];
  float2 ov; ov.x = ax / den; ov.y = ay / den;
  *(float2*)(aggx + (size_t)blockIdx.x * 512 + g * 128 + lane * 2) = ov;
}

// ---------- x3 = LN(head-blocked aggx @ Wg + bg)  register-tiled 4x4, W in LDS ----------
__global__ __launch_bounds__(256) void k_proj(const float* __restrict__ aggx,
                                              const float* __restrict__ Wg,
                                              const float* __restrict__ bg,
                                              const float* __restrict__ gam,
                                              const float* __restrict__ bet,
                                              float* __restrict__ x3, int nbase,
                                              int nrows) {
  // xs: 16 rows x 4 heads x 132 (pad 128->132); ws: 16-row W k-tile shared by 4 waves
  __shared__ float xs[16][4 * 132];
  __shared__ float ws[16][256];
  const int r0 = blockIdx.x * 16;
  const int t = threadIdx.x;
  const int cq = t & 63, rq = t >> 6;
  const int h = cq >> 4;  // head of this thread's 4 output cols
  for (int idx = t; idx < 16 * 128; idx += 256) {
    int r = idx >> 7;
    int p = (idx & 127) << 2;     // element 0..508 step 4 within 512-row
    int hh = p >> 7, k = p & 127; // never crosses a head boundary (128%4==0)
    float4 v = (r0 + r < nrows)
                   ? *(const float4*)(aggx + (size_t)(r0 + r) * 512 + p)
                   : make_float4(0.f, 0.f, 0.f, 0.f);
    *(float4*)&xs[r][hh * 132 + k] = v;
  }
  float acc[4][4];
#pragma unroll
  for (int i = 0; i < 4; i++)
#pragma unroll
    for (int j = 0; j < 4; j++) acc[i][j] = 0.f;
  for (int k0 = 0; k0 < 128; k0 += 16) {
    __syncthreads();  // xs ready (first iter) / previous ws consumed (later iters)
    // stage W rows k0..k0+15 (16KB) cooperatively, coalesced
    for (int idx = t; idx < 16 * 64; idx += 256) {
      int r = idx >> 6, p = (idx & 63) << 2;
      *(float4*)&ws[r][p] = *(const float4*)(Wg + (size_t)(k0 + r) * 256 + p);
    }
    __syncthreads();
#pragma unroll
    for (int kk = 0; kk < 16; kk += 4) {
      float4 xk[4], wk[4];
#pragma unroll
      for (int i = 0; i < 4; i++)
        xk[i] = *(const float4*)&xs[rq * 4 + i][h * 132 + k0 + kk];
#pragma unroll
      for (int k2 = 0; k2 < 4; k2++)
        wk[k2] = *(const float4*)&ws[kk + k2][cq * 4];
#pragma unroll
      for (int k2 = 0; k2 < 4; k2++) {
        const float* wf = (const float*)&wk[k2];
#pragma unroll
        for (int i = 0; i < 4; i++) {
          const float* xf = (const float*)&xk[i];
          float xv = xf[k2];
#pragma unroll
          for (int j = 0; j < 4; j++) acc[i][j] = fmaf(xv, wf[j], acc[i][j]);
        }
      }
    }
  }
  // epilogue: +bg, LayerNorm per row (row spans exactly one wave: 64 lanes x 4 cols)
  float4 bgv = *(const float4*)(bg + cq * 4);
  float4 gav = *(const float4*)(gam + cq * 4);
  float4 bev = *(const float4*)(bet + cq * 4);
  const float* bgf = (const float*)&bgv;
  const float* gaf = (const float*)&gav;
  const float* bef = (const float*)&bev;
#pragma unroll
  for (int i = 0; i < 4; i++) {
    float a[4], s = 0.f;
#pragma unroll
    for (int j = 0; j < 4; j++) { a[j] = acc[i][j] + bgf[j]; s += a[j]; }
    float mu = wave_sum(s) * (1.f / 256.f);
    float s2 = 0.f;
#pragma unroll
    for (int j = 0; j < 4; j++) { float d = a[j] - mu; s2 += d * d; }
    float rs = rsqrtf(wave_sum(s2) * (1.f / 256.f) + 1e-5f);
    int r = r0 + rq * 4 + i;
    if (r < nrows) {
      float4 ov;
      ov.x = fmaf(gaf[0] * (a[0] - mu), rs, bef[0]);
      ov.y = fmaf(gaf[1] * (a[1] - mu), rs, bef[1]);
      ov.z = fmaf(gaf[2] * (a[2] - mu), rs, bef[2]);
      ov.w = fmaf(gaf[3] * (a[3] - mu), rs, bef[3]);
      *(float4*)(x3 + (size_t)(nbase + r) * 256 + cq * 4) = ov;
    }
  }
}

// ---------- gate = relu(x3@Wgt1+bgt1)@Wgt2+bgt2  register-tiled 4x4, W in LDS ----------
__global__ __launch_bounds__(256) void k_gate(const float* __restrict__ x3,
                                              const float* __restrict__ Wgt1,
                                              const float* __restrict__ bgt1,
                                              const float* __restrict__ Wgt2,
                                              const float* __restrict__ bgt2,
                                              float* __restrict__ gate) {
  __shared__ float xs[16][256];  // 16KB node tile
  __shared__ float ws[16][256];  // 16KB W k-tile shared by 4 waves
  const int n0 = blockIdx.x * 16;
  const int t = threadIdx.x;
  const int cq = t & 63, rq = t >> 6;
  for (int idx = t; idx < 16 * 64; idx += 256) {
    int r = idx >> 6, p = (idx & 63) << 2;
    *(float4*)&xs[r][p] = *(const float4*)(x3 + (size_t)(n0 + r) * 256 + p);
  }
  float acc[4][4];
#pragma unroll
  for (int i = 0; i < 4; i++)
#pragma unroll
    for (int j = 0; j < 4; j++) acc[i][j] = 0.f;
  for (int k0 = 0; k0 < 256; k0 += 16) {
    __syncthreads();  // xs ready (first iter) / previous ws consumed (later iters)
    for (int idx = t; idx < 16 * 64; idx += 256) {
      int r = idx >> 6, p = (idx & 63) << 2;
      *(float4*)&ws[r][p] = *(const float4*)(Wgt1 + (size_t)(k0 + r) * 256 + p);
    }
    __syncthreads();
#pragma unroll
    for (int kk = 0; kk < 16; kk += 4) {
      float4 xk[4], wk[4];
#pragma unroll
      for (int i = 0; i < 4; i++)
        xk[i] = *(const float4*)&xs[rq * 4 + i][k0 + kk];
#pragma unroll
      for (int k2 = 0; k2 < 4; k2++)
        wk[k2] = *(const float4*)&ws[kk + k2][cq * 4];
#pragma unroll
      for (int k2 = 0; k2 < 4; k2++) {
        const float* wf = (const float*)&wk[k2];
#pragma unroll
        for (int i = 0; i < 4; i++) {
          const float* xf = (const float*)&xk[i];
          float xv = xf[k2];
#pragma unroll
          for (int j = 0; j < 4; j++) acc[i][j] = fmaf(xv, wf[j], acc[i][j]);
        }
      }
    }
  }
  // epilogue: relu(acc+b1)*w2, sum cols, per-wave reduce (row = one wave)
  float4 b1v = *(const float4*)(bgt1 + cq * 4);
  float4 w2v = *(const float4*)(Wgt2 + cq * 4);
  const float* b1f = (const float*)&b1v;
  const float* w2f = (const float*)&w2v;
  float b2 = bgt2[0];
#pragma unroll
  for (int i = 0; i < 4; i++) {
    float s = 0.f;
#pragma unroll
    for (int j = 0; j < 4; j++)
      s = fmaf(fmaxf(acc[i][j] + b1f[j], 0.f), w2f[j], s);
    s = wave_sum(s);
    if (cq == 0) gate[n0 + rq * 4 + i] = s + b2;
  }
}

// ---------- global max of gate ----------
__global__ void k_gmax(const float* __restrict__ gate, float* __restrict__ scal) {
  __shared__ float red[4];
  int i = blockIdx.x * 256 + threadIdx.x;
  float v = (i < NNODES) ? gate[i] : -3.0e38f;
  v = wave_max(v);
  __syncthreads();
  if ((threadIdx.x & 63) == 0) red[threadIdx.x >> 6] = v;
  __syncthreads();
  if (threadIdx.x == 0) {
    float m = fmaxf(fmaxf(red[0], red[1]), fmaxf(red[2], red[3]));
    atomicMaxFloat(&scal[0], m);
  }
}

// ---------- softmax-weighted pooling (unnormalized) ----------
__global__ void k_pool(const float* __restrict__ x3, const float* __restrict__ gate,
                       const float* __restrict__ scal, float* __restrict__ pooled) {
  const int c = threadIdx.x;  // 256
  const float gmax = scal[0];
  float acc = 0.f, zl = 0.f;
  for (int node = blockIdx.x; node < NNODES; node += gridDim.x) {
    float wv = __expf(gate[node] - gmax);
    if (c == 0) zl += wv;
    acc = fmaf(wv, x3[(size_t)node * 256 + c], acc);
  }
  atomicAdd(&pooled[c], acc);
  if (c == 0) atomicAdd((float*)&scal[1], zl);
}

// ---------- final: out = relu((pooled/Z) @ Wm + bm) ----------
__global__ void k_out(const float* __restrict__ pooled, const float* __restrict__ scal,
                      const float* __restrict__ Wm, const float* __restrict__ bm,
                      float* __restrict__ out) {
  __shared__ float p[256];
  const int j = threadIdx.x;
  p[j] = pooled[j] / scal[1];
  __syncthreads();
  float acc = bm[j];
  for (int k = 0; k < 256; k++) acc = fmaf(p[k], Wm[k * 256 + j], acc);
  out[j] = fmaxf(acc, 0.f);
}

extern "C" void kernel_launch(void* const* d_in, const int* in_sizes, int n_in,
                              void* d_out, int out_size, void* d_ws, size_t ws_size,
                              hipStream_t stream) {
  const float* x     = (const float*)d_in[0];
  const int*   ei    = (const int*)d_in[1];
  const float* W1    = (const float*)d_in[2];
  const float* b1    = (const float*)d_in[3];
  const float* W2    = (const float*)d_in[4];
  const float* b2    = (const float*)d_in[5];
  const float* Wg    = (const float*)d_in[6];
  const float* a_src = (const float*)d_in[7];
  const float* a_dst = (const float*)d_in[8];
  const float* bg    = (const float*)d_in[9];
  const float* ln1g  = (const float*)d_in[10];
  const float* ln1b  = (const float*)d_in[11];
  const float* ln2g  = (const float*)d_in[12];
  const float* ln2b  = (const float*)d_in[13];
  const float* ln3g  = (const float*)d_in[14];
  const float* ln3b  = (const float*)d_in[15];
  const float* Wgt1  = (const float*)d_in[16];
  const float* bgt1  = (const float*)d_in[17];
  const float* Wgt2  = (const float*)d_in[18];
  const float* bgt2  = (const float*)d_in[19];
  const float* Wm    = (const float*)d_in[20];
  const float* bm    = (const float*)d_in[21];

  float* out = (float*)d_out;   // [256]
  float* x3  = out + 256;       // [N,256]

  const int* src = ei;
  const int* dst = ei + NEDGES;

  char* wsb = (char*)d_ws;
  size_t off = 0;
  auto carve = [&](size_t bytes) -> void* {
    void* p = wsb + off;
    off += (bytes + 255) & ~(size_t)255;
    return p;
  };
  int*   deg    = (int*)carve((size_t)NNODES * 4);
  int*   offs   = (int*)carve((size_t)(NNODES + 1) * 4);
  int*   cursor = (int*)carve((size_t)NNODES * 4);
  int*   csr    = (int*)carve((size_t)NEDGES * 4);
  float* dinv   = (float*)carve((size_t)NNODES * 4);
  int*   bsum   = (int*)carve(256 * 4);
  int*   bbase  = (int*)carve(256 * 4);
  float* bufA   = (float*)carve((size_t)NNODES * 256 * 4);  // 51.2MB: x1|agg1|agg0, later aggx
  float* x2     = (float*)carve((size_t)NNODES * 128 * 4);
  float* ssrc   = (float*)carve((size_t)NNODES * 4 * 4);
  float* sdst   = (float*)carve((size_t)NNODES * 4 * 4);
  float* u      = (float*)carve(1024 * 4);
  float* gate   = (float*)carve((size_t)NNODES * 4);
  float* pooled = (float*)carve(256 * 4);
  float* scal   = (float*)carve(2 * 4);

  float* x1   = bufA;                        // [N,64]
  float* agg1 = bufA + (size_t)NNODES * 64;  // [N,64]
  float* agg0 = bufA + (size_t)NNODES * 128; // [N,3]
  float* aggx = bufA;                        // [25000,512] per chunk

  // graph build (hierarchical parallel scan)
  k_init<<<(NNODES + 255) / 256, 256, 0, stream>>>(deg, scal, pooled);
  k_deg<<<NEDGES / 256, 256, 0, stream>>>(dst, deg);
  k_scan1<<<NB, 256, 0, stream>>>(deg, bsum);
  k_scan2<<<1, 256, 0, stream>>>(bsum, bbase);
  k_scan3<<<NB, 256, 0, stream>>>(deg, bbase, offs, cursor, dinv);
  k_fill<<<NEDGES / 256, 256, 0, stream>>>(src, dst, cursor, csr);

  // GCN layer 1: aggregate in input space (3-dim), then project+LN
  k_agg3<<<(NNODES + 255) / 256, 256, 0, stream>>>(x, dinv, offs, csr, agg0);
  k_mlp<3, 64, 16, true><<<NNODES / 16, 64, 0, stream>>>(agg0, W1, b1, ln1g, ln1b, x1);

  // GCN layer 2: aggregate x1 (64-dim), then project+LN
  k_agg<1, 4><<<NNODES, 256, 0, stream>>>(x1, dinv, offs, csr, agg1);
  k_mlp<64, 128, 8, true><<<NNODES / 8, 128, 0, stream>>>(agg1, W2, b2, ln2g, ln2b, x2);

  // GAT: scores from x2 via u = Wg @ a, aggregate x2, then project+LN
  k_uvec<<<1, 512, 0, stream>>>(Wg, a_src, a_dst, u);
  k_scores<<<(NNODES + 3) / 4, 256, 0, stream>>>(x2, u, ssrc, sdst);
  for (int c = 0; c < 2; c++) {
    int nbase = c * (NNODES / 2);
    int nrows = NNODES / 2;
    k_gatagg<<<nrows, 256, 0, stream>>>(x2, ssrc, sdst, offs, csr, aggx, nbase);
    k_proj<<<(nrows + 15) / 16, 256, 0, stream>>>(aggx, Wg, bg, ln3g, ln3b, x3,
                                                  nbase, nrows);
  }

  // gate MLP + softmax pooling + output
  k_gate<<<NNODES / 16, 256, 0, stream>>>(x3, Wgt1, bgt1, Wgt2, bgt2, gate);
  k_gmax<<<(NNODES + 255) / 256, 256, 0, stream>>>(gate, scal);
  k_pool<<<256, 256, 0, stream>>>(x3, gate, scal, pooled);
  k_out<<<1, 256, 0, stream>>>(pooled, scal, Wm, bm, out);
}

// Round 15
// 776.524 us; speedup vs baseline: 1.0710x; 1.0710x over previous
//
#include <hip/hip_runtime.h>
#include <math.h>

#define NNODES 50000
#define NEDGES 800000
#define NB 196  // ceil(NNODES/256)

// ---------- reduction helpers (wave = 64 lanes) ----------
__device__ __forceinline__ float wave_sum(float v) {
#pragma unroll
  for (int o = 32; o > 0; o >>= 1) v += __shfl_xor(v, o, 64);
  return v;
}
__device__ __forceinline__ float wave_max(float v) {
#pragma unroll
  for (int o = 32; o > 0; o >>= 1) v = fmaxf(v, __shfl_xor(v, o, 64));
  return v;
}
__device__ __forceinline__ int wave_isum(int v) {
#pragma unroll
  for (int o = 32; o > 0; o >>= 1) v += __shfl_xor(v, o, 64);
  return v;
}
__device__ __forceinline__ int wave_iscan(int v, int lane) {  // inclusive
#pragma unroll
  for (int o = 1; o < 64; o <<= 1) {
    int u = __shfl_up(v, o, 64);
    if (lane >= o) v += u;
  }
  return v;
}
template <int NW>
__device__ __forceinline__ float block_sum(float v, float* red) {
  v = wave_sum(v);
  __syncthreads();
  if ((threadIdx.x & 63) == 0) red[threadIdx.x >> 6] = v;
  __syncthreads();
  float s = 0.f;
#pragma unroll
  for (int i = 0; i < NW; i++) s += red[i];
  return s;
}

__device__ __forceinline__ float leaky02(float x) { return x > 0.f ? x : 0.2f * x; }

__device__ __forceinline__ void atomicMaxFloat(float* addr, float val) {
  if (val >= 0.f)
    atomicMax((int*)addr, __float_as_int(val));
  else
    atomicMin((unsigned int*)addr, __float_as_uint(val));
}

// ---------- init ----------
__global__ void k_init(int* __restrict__ deg, float* __restrict__ scal,
                       float* __restrict__ pooled) {
  int i = blockIdx.x * blockDim.x + threadIdx.x;
  if (i < NNODES) deg[i] = 0;
  if (i < 256) pooled[i] = 0.f;
  if (i == 0) { scal[0] = -3.0e38f; scal[1] = 0.f; }
}

// ---------- degree count (in-degree by dst) ----------
__global__ void k_deg(const int* __restrict__ dst, int* __restrict__ deg) {
  int e = blockIdx.x * blockDim.x + threadIdx.x;
  if (e < NEDGES) atomicAdd(&deg[dst[e]], 1);
}

// ---------- hierarchical scan stage 1: per-block degree sums ----------
__global__ __launch_bounds__(256) void k_scan1(const int* __restrict__ deg,
                                               int* __restrict__ bsum) {
  __shared__ int red[4];
  int i = blockIdx.x * 256 + threadIdx.x;
  int v = (i < NNODES) ? deg[i] : 0;
  v = wave_isum(v);
  if ((threadIdx.x & 63) == 0) red[threadIdx.x >> 6] = v;
  __syncthreads();
  if (threadIdx.x == 0) bsum[blockIdx.x] = red[0] + red[1] + red[2] + red[3];
}

// ---------- stage 2: exclusive scan of block sums (1 block) ----------
__global__ __launch_bounds__(256) void k_scan2(const int* __restrict__ bsum,
                                               int* __restrict__ bbase) {
  __shared__ int wsum[4];
  const int t = threadIdx.x, lane = t & 63, w = t >> 6;
  int v = (t < NB) ? bsum[t] : 0;
  int incl = wave_iscan(v, lane);
  if (lane == 63) wsum[w] = incl;
  __syncthreads();
  int wb = 0;
  for (int k = 0; k < w; k++) wb += wsum[k];
  if (t < NB) bbase[t] = wb + incl - v;  // exclusive prefix
}

// ---------- stage 3: per-node offsets + cursor + dinv (coalesced) ----------
__global__ __launch_bounds__(256) void k_scan3(const int* __restrict__ deg,
                                               const int* __restrict__ bbase,
                                               int* __restrict__ offs,
                                               int* __restrict__ cursor,
                                               float* __restrict__ dinv) {
  __shared__ int wsum[4];
  const int i = blockIdx.x * 256 + threadIdx.x;
  const int lane = threadIdx.x & 63, w = threadIdx.x >> 6;
  int d = (i < NNODES) ? deg[i] : 0;
  int incl = wave_iscan(d, lane);
  if (lane == 63) wsum[w] = incl;
  __syncthreads();
  int wb = 0;
  for (int k = 0; k < w; k++) wb += wsum[k];
  int excl = bbase[blockIdx.x] + wb + incl - d;
  if (i < NNODES) {
    offs[i] = excl;
    cursor[i] = excl;
    dinv[i] = rsqrtf((float)(d + 1));  // +1 self-loop
    if (i == NNODES - 1) offs[NNODES] = excl + d;
  }
}

// ---------- CSR fill ----------
__global__ void k_fill(const int* __restrict__ src, const int* __restrict__ dst,
                       int* __restrict__ cursor, int* __restrict__ csr) {
  int e = blockIdx.x * blockDim.x + threadIdx.x;
  if (e >= NEDGES) return;
  int d = dst[e];
  int p = atomicAdd(&cursor[d], 1);
  csr[p] = src[e];
}

// ---------- agg0 = Ahat @ x  (3-dim rows, thread per node) ----------
__global__ void k_agg3(const float* __restrict__ x, const float* __restrict__ dinv,
                       const int* __restrict__ offs, const int* __restrict__ csr,
                       float* __restrict__ agg0) {
  int n = blockIdx.x * blockDim.x + threadIdx.x;
  if (n >= NNODES) return;
  float di = dinv[n];
  float a0 = di * x[n * 3], a1 = di * x[n * 3 + 1], a2 = di * x[n * 3 + 2];
  int lo = offs[n], hi = offs[n + 1];
  int p = lo;
  int snext = (p < hi) ? csr[p] : 0;
  while (p < hi) {
    int s = snext; p++; if (p < hi) snext = csr[p];
    float w = dinv[s];
    a0 = fmaf(w, x[s * 3], a0);
    a1 = fmaf(w, x[s * 3 + 1], a1);
    a2 = fmaf(w, x[s * 3 + 2], a2);
  }
  agg0[n * 3] = di * a0; agg0[n * 3 + 1] = di * a1; agg0[n * 3 + 2] = di * a2;
}

// ---------- aggD = Ahat @ h  (D = 64*VEC, block per node, NG edge-groups) ----------
template <int VEC, int NG>
__global__ __launch_bounds__(64 * NG) void k_agg(const float* __restrict__ h,
                                                 const float* __restrict__ dinv,
                                                 const int* __restrict__ offs,
                                                 const int* __restrict__ csr,
                                                 float* __restrict__ out) {
  __shared__ float lacc[NG][64][VEC + 1];
  const int n = blockIdx.x;
  const int lane = threadIdx.x & 63, g = threadIdx.x >> 6;
  const float di = dinv[n];
  float acc[VEC];
#pragma unroll
  for (int v = 0; v < VEC; v++) acc[v] = 0.f;
  if (g == 0) {
    const float* r = h + (size_t)n * (64 * VEC) + lane * VEC;
#pragma unroll
    for (int v = 0; v < VEC; v++) acc[v] = di * r[v];
  }
  const int lo = offs[n], hi = offs[n + 1];
  int p = lo + g;
  int snext = (p < hi) ? csr[p] : 0;
  while (p < hi) {
    int s = snext; p += NG; if (p < hi) snext = csr[p];
    float w = dinv[s];
    const float* r = h + (size_t)s * (64 * VEC) + lane * VEC;
#pragma unroll
    for (int v = 0; v < VEC; v++) acc[v] = fmaf(w, r[v], acc[v]);
  }
#pragma unroll
  for (int v = 0; v < VEC; v++) lacc[g][lane][v] = acc[v];
  __syncthreads();
  if (g == 0) {
#pragma unroll
    for (int G = 1; G < NG; G++)
#pragma unroll
      for (int v = 0; v < VEC; v++) acc[v] += lacc[G][lane][v];
    float* o = out + (size_t)n * (64 * VEC) + lane * VEC;
#pragma unroll
    for (int v = 0; v < VEC; v++) o[v] = di * acc[v];
  }
}

// ---------- Y = LN(act(X@W + b))  node-tiled, fused LN ----------
template <int K, int M, int NT, bool RELU>
__global__ void k_mlp(const float* __restrict__ X, const float* __restrict__ W,
                      const float* __restrict__ b, const float* __restrict__ gam,
                      const float* __restrict__ bet, float* __restrict__ Y) {
  constexpr int NW = M / 64;
  __shared__ float xs[NT * K];
  __shared__ float red[NW];
  const int n0 = blockIdx.x * NT;
  const int j = threadIdx.x;
  const float4* Xt = (const float4*)(X + (size_t)n0 * K);
  for (int i = j; i < NT * K / 4; i += M) ((float4*)xs)[i] = Xt[i];
  __syncthreads();
  float acc[NT];
  float bj = b[j];
#pragma unroll
  for (int r = 0; r < NT; r++) acc[r] = bj;
  for (int k = 0; k < K; k++) {
    float wk = W[k * M + j];
#pragma unroll
    for (int r = 0; r < NT; r++) acc[r] = fmaf(xs[r * K + k], wk, acc[r]);
  }
  float gj = gam[j], btj = bet[j];
  for (int r = 0; r < NT; r++) {
    float a = RELU ? fmaxf(acc[r], 0.f) : acc[r];
    float mu = block_sum<NW>(a, red) * (1.f / M);
    float d = a - mu;
    float var = block_sum<NW>(d * d, red) * (1.f / M);
    Y[(size_t)(n0 + r) * M + j] = fmaf(gj * d, rsqrtf(var + 1e-5f), btj);
  }
}

// ---------- u vectors: u_src[h,k] = sum_c Wg[k, h*64+c] * a_src[h,c] ----------
__global__ void k_uvec(const float* __restrict__ Wg, const float* __restrict__ a_src,
                       const float* __restrict__ a_dst, float* __restrict__ u) {
  const int t = threadIdx.x;  // 512
  const int hh = t >> 7, k = t & 127;
  float us = 0.f, ud = 0.f;
  for (int c = 0; c < 64; c++) {
    float w = Wg[k * 256 + hh * 64 + c];
    us = fmaf(w, a_src[hh * 64 + c], us);
    ud = fmaf(w, a_dst[hh * 64 + c], ud);
  }
  u[t] = us;
  u[512 + t] = ud;
}

// ---------- per-node attention scores: ssrc/sdst[n,h] = x2[n]·u ----------
__global__ __launch_bounds__(256) void k_scores(const float* __restrict__ x2,
                                                const float* __restrict__ u,
                                                float* __restrict__ ssrc,
                                                float* __restrict__ sdst) {
  __shared__ float us[1024];
  const int t = threadIdx.x;
  for (int i = t; i < 1024; i += 256) us[i] = u[i];
  __syncthreads();
  const int n = blockIdx.x * 4 + (t >> 6);
  const int lane = t & 63;
  if (n >= NNODES) return;
  float2 xv = *(const float2*)(x2 + (size_t)n * 128 + lane * 2);
  float d[8];
#pragma unroll
  for (int h = 0; h < 4; h++) {
    d[h] = xv.x * us[h * 128 + lane * 2] + xv.y * us[h * 128 + lane * 2 + 1];
    d[4 + h] = xv.x * us[512 + h * 128 + lane * 2] + xv.y * us[512 + h * 128 + lane * 2 + 1];
  }
#pragma unroll
  for (int o = 32; o > 0; o >>= 1) {
#pragma unroll
    for (int i = 0; i < 8; i++) d[i] += __shfl_xor(d[i], o, 64);
  }
  if (lane == 0) {
    *(float4*)(ssrc + (size_t)n * 4) = make_float4(d[0], d[1], d[2], d[3]);
    *(float4*)(sdst + (size_t)n * 4) = make_float4(d[4], d[5], d[6], d[7]);
  }
}

// ---------- GAT aggregate in x2-space: aggx[n, h, k] = sum_s alpha_s,h x2[s,k] ----------
__global__ __launch_bounds__(256) void k_gatagg(const float* __restrict__ x2,
                                                const float* __restrict__ ssrc,
                                                const float* __restrict__ sdst,
                                                const int* __restrict__ offs,
                                                const int* __restrict__ csr,
                                                float* __restrict__ aggx, int nbase) {
  __shared__ float lm[4][4];
  __shared__ float lden[4][4];
  __shared__ float lacc[4][64][9];
  const int n = nbase + blockIdx.x;
  const int t = threadIdx.x;
  const int lane = t & 63, g = t >> 6;
  const float4 sd = *(const float4*)(sdst + (size_t)n * 4);
  const int lo = offs[n], hi = offs[n + 1];
  float m0 = -3.4e38f, m1 = -3.4e38f, m2 = -3.4e38f, m3 = -3.4e38f;
  float e0x = 0.f, e0y = 0.f, e0z = 0.f, e0w = 0.f;
  if (g == 0) {
    float4 s0 = *(const float4*)(ssrc + (size_t)n * 4);
    e0x = leaky02(s0.x + sd.x); e0y = leaky02(s0.y + sd.y);
    e0z = leaky02(s0.z + sd.z); e0w = leaky02(s0.w + sd.w);
    m0 = e0x; m1 = e0y; m2 = e0z; m3 = e0w;
  }
  for (int p = lo + g; p < hi; p += 4) {
    int s = csr[p];
    float4 ss = *(const float4*)(ssrc + (size_t)s * 4);
    m0 = fmaxf(m0, leaky02(ss.x + sd.x));
    m1 = fmaxf(m1, leaky02(ss.y + sd.y));
    m2 = fmaxf(m2, leaky02(ss.z + sd.z));
    m3 = fmaxf(m3, leaky02(ss.w + sd.w));
  }
  if (lane == 0) { lm[g][0] = m0; lm[g][1] = m1; lm[g][2] = m2; lm[g][3] = m3; }
  __syncthreads();
  const float M0 = fmaxf(fmaxf(lm[0][0], lm[1][0]), fmaxf(lm[2][0], lm[3][0]));
  const float M1 = fmaxf(fmaxf(lm[0][1], lm[1][1]), fmaxf(lm[2][1], lm[3][1]));
  const float M2 = fmaxf(fmaxf(lm[0][2], lm[1][2]), fmaxf(lm[2][2], lm[3][2]));
  const float M3 = fmaxf(fmaxf(lm[0][3], lm[1][3]), fmaxf(lm[2][3], lm[3][3]));
  float den0 = 0.f, den1 = 0.f, den2 = 0.f, den3 = 0.f;
  float a0x = 0.f, a0y = 0.f, a1x = 0.f, a1y = 0.f;
  float a2x = 0.f, a2y = 0.f, a3x = 0.f, a3y = 0.f;
  if (g == 0) {
    float2 xv = *(const float2*)(x2 + (size_t)n * 128 + lane * 2);
    float w;
    w = __expf(e0x - M0); den0 = w; a0x = w * xv.x; a0y = w * xv.y;
    w = __expf(e0y - M1); den1 = w; a1x = w * xv.x; a1y = w * xv.y;
    w = __expf(e0z - M2); den2 = w; a2x = w * xv.x; a2y = w * xv.y;
    w = __expf(e0w - M3); den3 = w; a3x = w * xv.x; a3y = w * xv.y;
  }
  int p = lo + g;
  int snext = (p < hi) ? csr[p] : 0;
  while (p < hi) {
    int s = snext; p += 4; if (p < hi) snext = csr[p];
    float4 ss = *(const float4*)(ssrc + (size_t)s * 4);
    float2 xv = *(const float2*)(x2 + (size_t)s * 128 + lane * 2);
    float w0 = __expf(leaky02(ss.x + sd.x) - M0);
    float w1 = __expf(leaky02(ss.y + sd.y) - M1);
    float w2 = __expf(leaky02(ss.z + sd.z) - M2);
    float w3 = __expf(leaky02(ss.w + sd.w) - M3);
    den0 += w0; den1 += w1; den2 += w2; den3 += w3;
    a0x = fmaf(w0, xv.x, a0x); a0y = fmaf(w0, xv.y, a0y);
    a1x = fmaf(w1, xv.x, a1x); a1y = fmaf(w1, xv.y, a1y);
    a2x = fmaf(w2, xv.x, a2x); a2y = fmaf(w2, xv.y, a2y);
    a3x = fmaf(w3, xv.x, a3x); a3y = fmaf(w3, xv.y, a3y);
  }
  if (lane == 0) { lden[g][0] = den0; lden[g][1] = den1; lden[g][2] = den2; lden[g][3] = den3; }
  lacc[g][lane][0] = a0x; lacc[g][lane][1] = a0y;
  lacc[g][lane][2] = a1x; lacc[g][lane][3] = a1y;
  lacc[g][lane][4] = a2x; lacc[g][lane][5] = a2y;
  lacc[g][lane][6] = a3x; lacc[g][lane][7] = a3y;
  __syncthreads();
  // group g finalizes head g
  float den = lden[0][g] + lden[1][g] + lden[2][g] + lden[3][g] + 1e-16f;
  float ax = lacc[0][lane][2 * g] + lacc[1][lane][2 * g] + lacc[2][lane][2 * g] + lacc[3][lane][2 * g];
  float ay = lacc[0][lane][2 * g + 1] + lacc[1][lane][2 * g + 1] + lacc[2][lane][2 * g + 1] + lacc[3][lane][2 * g + 1];
  float2 ov; ov.x = ax / den; ov.y = ay / den;
  *(float2*)(aggx + (size_t)blockIdx.x * 512 + g * 128 + lane * 2) = ov;
}

// ---------- x3 = LN(head-blocked aggx @ Wg + bg)  register-tiled 4x4 (r13 form) ----------
__global__ __launch_bounds__(256) void k_proj(const float* __restrict__ aggx,
                                              const float* __restrict__ Wg,
                                              const float* __restrict__ bg,
                                              const float* __restrict__ gam,
                                              const float* __restrict__ bet,
                                              float* __restrict__ x3, int nbase,
                                              int nrows) {
  // xs: 16 rows x 4 heads x 132 (pad 128->132 to spread head bases across banks)
  __shared__ float xs[16][4 * 132];
  const int r0 = blockIdx.x * 16;
  const int t = threadIdx.x;
  const int cq = t & 63, rq = t >> 6;
  const int h = cq >> 4;  // head of this thread's 4 output cols
  for (int idx = t; idx < 16 * 128; idx += 256) {
    int r = idx >> 7;
    int p = (idx & 127) << 2;     // element 0..508 step 4 within 512-row
    int hh = p >> 7, k = p & 127; // never crosses a head boundary (128%4==0)
    float4 v = (r0 + r < nrows)
                   ? *(const float4*)(aggx + (size_t)(r0 + r) * 512 + p)
                   : make_float4(0.f, 0.f, 0.f, 0.f);
    *(float4*)&xs[r][hh * 132 + k] = v;
  }
  __syncthreads();
  float acc[4][4];
#pragma unroll
  for (int i = 0; i < 4; i++)
#pragma unroll
    for (int j = 0; j < 4; j++) acc[i][j] = 0.f;
  const float4* Wv = (const float4*)Wg;  // row k: float4 idx k*64 + cq
  for (int k0 = 0; k0 < 128; k0 += 4) {
    float4 xk[4], wk[4];
#pragma unroll
    for (int i = 0; i < 4; i++)
      xk[i] = *(const float4*)&xs[rq * 4 + i][h * 132 + k0];
#pragma unroll
    for (int kk = 0; kk < 4; kk++) wk[kk] = Wv[(size_t)(k0 + kk) * 64 + cq];
#pragma unroll
    for (int kk = 0; kk < 4; kk++) {
      const float* wf = (const float*)&wk[kk];
#pragma unroll
      for (int i = 0; i < 4; i++) {
        const float* xf = (const float*)&xk[i];
        float xv = xf[kk];
#pragma unroll
        for (int j = 0; j < 4; j++) acc[i][j] = fmaf(xv, wf[j], acc[i][j]);
      }
    }
  }
  // epilogue: +bg, LayerNorm per row (row spans exactly one wave: 64 lanes x 4 cols)
  float4 bgv = *(const float4*)(bg + cq * 4);
  float4 gav = *(const float4*)(gam + cq * 4);
  float4 bev = *(const float4*)(bet + cq * 4);
  const float* bgf = (const float*)&bgv;
  const float* gaf = (const float*)&gav;
  const float* bef = (const float*)&bev;
#pragma unroll
  for (int i = 0; i < 4; i++) {
    float a[4], s = 0.f;
#pragma unroll
    for (int j = 0; j < 4; j++) { a[j] = acc[i][j] + bgf[j]; s += a[j]; }
    float mu = wave_sum(s) * (1.f / 256.f);
    float s2 = 0.f;
#pragma unroll
    for (int j = 0; j < 4; j++) { float d = a[j] - mu; s2 += d * d; }
    float rs = rsqrtf(wave_sum(s2) * (1.f / 256.f) + 1e-5f);
    int r = r0 + rq * 4 + i;
    if (r < nrows) {
      float4 ov;
      ov.x = fmaf(gaf[0] * (a[0] - mu), rs, bef[0]);
      ov.y = fmaf(gaf[1] * (a[1] - mu), rs, bef[1]);
      ov.z = fmaf(gaf[2] * (a[2] - mu), rs, bef[2]);
      ov.w = fmaf(gaf[3] * (a[3] - mu), rs, bef[3]);
      *(float4*)(x3 + (size_t)(nbase + r) * 256 + cq * 4) = ov;
    }
  }
}

// ---------- gate = relu(x3@Wgt1+bgt1)@Wgt2+bgt2  NT=32, 8x4 per-thread tile ----------
__global__ __launch_bounds__(256) void k_gate(const float* __restrict__ x3,
                                              const float* __restrict__ Wgt1,
                                              const float* __restrict__ bgt1,
                                              const float* __restrict__ Wgt2,
                                              const float* __restrict__ bgt2,
                                              float* __restrict__ gate) {
  __shared__ float xs[32][256];  // 32KB node tile; each W float4 feeds 8 FMAs
  const int n0 = blockIdx.x * 32;
  const int t = threadIdx.x;
  const int cq = t & 63, rq = t >> 6;
  for (int idx = t; idx < 32 * 64; idx += 256) {
    int r = idx >> 6, p = (idx & 63) << 2;
    float4 v = (n0 + r < NNODES)
                   ? *(const float4*)(x3 + (size_t)(n0 + r) * 256 + p)
                   : make_float4(0.f, 0.f, 0.f, 0.f);
    *(float4*)&xs[r][p] = v;
  }
  __syncthreads();
  float acc[8][4];
#pragma unroll
  for (int i = 0; i < 8; i++)
#pragma unroll
    for (int j = 0; j < 4; j++) acc[i][j] = 0.f;
  const float4* Wv = (const float4*)Wgt1;
  for (int k0 = 0; k0 < 256; k0 += 4) {
    float4 xk[8], wk[4];
#pragma unroll
    for (int i = 0; i < 8; i++) xk[i] = *(const float4*)&xs[rq * 8 + i][k0];
#pragma unroll
    for (int kk = 0; kk < 4; kk++) wk[kk] = Wv[(size_t)(k0 + kk) * 64 + cq];
#pragma unroll
    for (int kk = 0; kk < 4; kk++) {
      const float* wf = (const float*)&wk[kk];
#pragma unroll
      for (int i = 0; i < 8; i++) {
        const float* xf = (const float*)&xk[i];
        float xv = xf[kk];
#pragma unroll
        for (int j = 0; j < 4; j++) acc[i][j] = fmaf(xv, wf[j], acc[i][j]);
      }
    }
  }
  // epilogue: relu(acc+b1)*w2, sum cols, per-wave reduce (each wave owns 8 rows)
  float4 b1v = *(const float4*)(bgt1 + cq * 4);
  float4 w2v = *(const float4*)(Wgt2 + cq * 4);
  const float* b1f = (const float*)&b1v;
  const float* w2f = (const float*)&w2v;
  float b2 = bgt2[0];
#pragma unroll
  for (int i = 0; i < 8; i++) {
    float s = 0.f;
#pragma unroll
    for (int j = 0; j < 4; j++)
      s = fmaf(fmaxf(acc[i][j] + b1f[j], 0.f), w2f[j], s);
    s = wave_sum(s);
    int n = n0 + rq * 8 + i;
    if (cq == 0 && n < NNODES) gate[n] = s + b2;
  }
}

// ---------- global max of gate ----------
__global__ void k_gmax(const float* __restrict__ gate, float* __restrict__ scal) {
  __shared__ float red[4];
  int i = blockIdx.x * 256 + threadIdx.x;
  float v = (i < NNODES) ? gate[i] : -3.0e38f;
  v = wave_max(v);
  __syncthreads();
  if ((threadIdx.x & 63) == 0) red[threadIdx.x >> 6] = v;
  __syncthreads();
  if (threadIdx.x == 0) {
    float m = fmaxf(fmaxf(red[0], red[1]), fmaxf(red[2], red[3]));
    atomicMaxFloat(&scal[0], m);
  }
}

// ---------- softmax-weighted pooling (unnormalized) ----------
__global__ void k_pool(const float* __restrict__ x3, const float* __restrict__ gate,
                       const float* __restrict__ scal, float* __restrict__ pooled) {
  const int c = threadIdx.x;  // 256
  const float gmax = scal[0];
  float acc = 0.f, zl = 0.f;
  for (int node = blockIdx.x; node < NNODES; node += gridDim.x) {
    float wv = __expf(gate[node] - gmax);
    if (c == 0) zl += wv;
    acc = fmaf(wv, x3[(size_t)node * 256 + c], acc);
  }
  atomicAdd(&pooled[c], acc);
  if (c == 0) atomicAdd((float*)&scal[1], zl);
}

// ---------- final: out = relu((pooled/Z) @ Wm + bm) ----------
__global__ void k_out(const float* __restrict__ pooled, const float* __restrict__ scal,
                      const float* __restrict__ Wm, const float* __restrict__ bm,
                      float* __restrict__ out) {
  __shared__ float p[256];
  const int j = threadIdx.x;
  p[j] = pooled[j] / scal[1];
  __syncthreads();
  float acc = bm[j];
  for (int k = 0; k < 256; k++) acc = fmaf(p[k], Wm[k * 256 + j], acc);
  out[j] = fmaxf(acc, 0.f);
}

extern "C" void kernel_launch(void* const* d_in, const int* in_sizes, int n_in,
                              void* d_out, int out_size, void* d_ws, size_t ws_size,
                              hipStream_t stream) {
  const float* x     = (const float*)d_in[0];
  const int*   ei    = (const int*)d_in[1];
  const float* W1    = (const float*)d_in[2];
  const float* b1    = (const float*)d_in[3];
  const float* W2    = (const float*)d_in[4];
  const float* b2    = (const float*)d_in[5];
  const float* Wg    = (const float*)d_in[6];
  const float* a_src = (const float*)d_in[7];
  const float* a_dst = (const float*)d_in[8];
  const float* bg    = (const float*)d_in[9];
  const float* ln1g  = (const float*)d_in[10];
  const float* ln1b  = (const float*)d_in[11];
  const float* ln2g  = (const float*)d_in[12];
  const float* ln2b  = (const float*)d_in[13];
  const float* ln3g  = (const float*)d_in[14];
  const float* ln3b  = (const float*)d_in[15];
  const float* Wgt1  = (const float*)d_in[16];
  const float* bgt1  = (const float*)d_in[17];
  const float* Wgt2  = (const float*)d_in[18];
  const float* bgt2  = (const float*)d_in[19];
  const float* Wm    = (const float*)d_in[20];
  const float* bm    = (const float*)d_in[21];

  float* out = (float*)d_out;   // [256]
  float* x3  = out + 256;       // [N,256]

  const int* src = ei;
  const int* dst = ei + NEDGES;

  char* wsb = (char*)d_ws;
  size_t off = 0;
  auto carve = [&](size_t bytes) -> void* {
    void* p = wsb + off;
    off += (bytes + 255) & ~(size_t)255;
    return p;
  };
  int*   deg    = (int*)carve((size_t)NNODES * 4);
  int*   offs   = (int*)carve((size_t)(NNODES + 1) * 4);
  int*   cursor = (int*)carve((size_t)NNODES * 4);
  int*   csr    = (int*)carve((size_t)NEDGES * 4);
  float* dinv   = (float*)carve((size_t)NNODES * 4);
  int*   bsum   = (int*)carve(256 * 4);
  int*   bbase  = (int*)carve(256 * 4);
  float* bufA   = (float*)carve((size_t)NNODES * 256 * 4);  // 51.2MB: x1|agg1|agg0, later aggx
  float* x2     = (float*)carve((size_t)NNODES * 128 * 4);
  float* ssrc   = (float*)carve((size_t)NNODES * 4 * 4);
  float* sdst   = (float*)carve((size_t)NNODES * 4 * 4);
  float* u      = (float*)carve(1024 * 4);
  float* gate   = (float*)carve((size_t)NNODES * 4);
  float* pooled = (float*)carve(256 * 4);
  float* scal   = (float*)carve(2 * 4);

  float* x1   = bufA;                        // [N,64]
  float* agg1 = bufA + (size_t)NNODES * 64;  // [N,64]
  float* agg0 = bufA + (size_t)NNODES * 128; // [N,3]
  float* aggx = bufA;                        // [25000,512] per chunk

  // graph build (hierarchical parallel scan)
  k_init<<<(NNODES + 255) / 256, 256, 0, stream>>>(deg, scal, pooled);
  k_deg<<<NEDGES / 256, 256, 0, stream>>>(dst, deg);
  k_scan1<<<NB, 256, 0, stream>>>(deg, bsum);
  k_scan2<<<1, 256, 0, stream>>>(bsum, bbase);
  k_scan3<<<NB, 256, 0, stream>>>(deg, bbase, offs, cursor, dinv);
  k_fill<<<NEDGES / 256, 256, 0, stream>>>(src, dst, cursor, csr);

  // GCN layer 1: aggregate in input space (3-dim), then project+LN
  k_agg3<<<(NNODES + 255) / 256, 256, 0, stream>>>(x, dinv, offs, csr, agg0);
  k_mlp<3, 64, 16, true><<<NNODES / 16, 64, 0, stream>>>(agg0, W1, b1, ln1g, ln1b, x1);

  // GCN layer 2: aggregate x1 (64-dim), then project+LN
  k_agg<1, 4><<<NNODES, 256, 0, stream>>>(x1, dinv, offs, csr, agg1);
  k_mlp<64, 128, 8, true><<<NNODES / 8, 128, 0, stream>>>(agg1, W2, b2, ln2g, ln2b, x2);

  // GAT: scores from x2 via u = Wg @ a, aggregate x2, then project+LN
  k_uvec<<<1, 512, 0, stream>>>(Wg, a_src, a_dst, u);
  k_scores<<<(NNODES + 3) / 4, 256, 0, stream>>>(x2, u, ssrc, sdst);
  for (int c = 0; c < 2; c++) {
    int nbase = c * (NNODES / 2);
    int nrows = NNODES / 2;
    k_gatagg<<<nrows, 256, 0, stream>>>(x2, ssrc, sdst, offs, csr, aggx, nbase);
    k_proj<<<(nrows + 15) / 16, 256, 0, stream>>>(aggx, Wg, bg, ln3g, ln3b, x3,
                                                  nbase, nrows);
  }

  // gate MLP + softmax pooling + output
  k_gate<<<(NNODES + 31) / 32, 256, 0, stream>>>(x3, Wgt1, bgt1, Wgt2, bgt2, gate);
  k_gmax<<<(NNODES + 255) / 256, 256, 0, stream>>>(gate, scal);
  k_pool<<<256, 256, 0, stream>>>(x3, gate, scal, pooled);
  k_out<<<1, 256, 0, stream>>>(pooled, scal, Wm, bm, out);
}